// Round 3
// baseline (904.066 us; speedup 1.0000x reference)
//
#include <hip/hip_runtime.h>
#include <hip/hip_cooperative_groups.h>
#include <math.h>

namespace cg = cooperative_groups;

#define BN_EPS 1e-3f

// Fused cooperative geometry: 1024 blocks x 256 threads (4 blocks/CU -> all
// co-resident at <=128 VGPR, comfortably satisfiable).
#define NBLK 1024
#define NTHR 256

// GEMV chunking: 2048 chunks = (2N/GB_ROWS=256 row-chunks) x (N/GB_COLS=8 col-blocks).
// Each block processes 2 chunks.
#define GB_ROWS 64
#define GB_COLS 1024

__global__ __launch_bounds__(NTHR, 4)
void fused_gcn_kernel(const float* __restrict__ x,
                      const int* __restrict__ adj,
                      const float* __restrict__ bn_gamma,
                      const float* __restrict__ bn_beta,
                      const float* __restrict__ bn_mean,
                      const float* __restrict__ bn_var,
                      const float* __restrict__ W,
                      const float* __restrict__ b,
                      float* __restrict__ part,   // [2N/GB_ROWS][N] ws
                      float* __restrict__ h_bn,   // [2N] ws
                      float* __restrict__ out,    // [N]
                      int N, int K)
{
    cg::grid_group grid = cg::this_grid();
    __shared__ float hs[GB_ROWS];
    __shared__ float sm[4][64];

    const int tid  = threadIdx.x;
    const int lane = tid & 63;
    const int wv   = tid >> 6;

    // ---- Phase A: aggregation + BatchNorm. One 64-lane wave per node,
    // 8 nodes per block (2 per wave). adj row = coalesced 256B read; x is
    // 32KB -> L1/L2 resident for the random gathers.
    const int nodes_per_blk = (N + NBLK - 1) / NBLK;          // 8
    for (int ni = 0; ni < nodes_per_blk; ni += 4) {
        int node = blockIdx.x * nodes_per_blk + ni + wv;
        if (node < N) {
            float s = 0.0f;
            for (int k = lane; k < K; k += 64)
                s += x[adj[(size_t)node * K + k]];
#pragma unroll
            for (int off = 32; off > 0; off >>= 1)
                s += __shfl_down(s, off, 64);
            if (lane == 0) {
                float xi  = x[node];
                float agg = xi + s;
                float sc0 = rsqrtf(bn_var[node] + BN_EPS) * bn_gamma[node];
                h_bn[node] = (xi - bn_mean[node]) * sc0 + bn_beta[node];
                int j = N + node;
                float sc1 = rsqrtf(bn_var[j] + BN_EPS) * bn_gamma[j];
                h_bn[j] = (agg - bn_mean[j]) * sc1 + bn_beta[j];
            }
        }
    }

    grid.sync();

    // ---- Phase B: split-K GEMV partials, atomic-free.
    // chunk c -> col-block (c & 7), row-chunk (c >> 3). 2 chunks per block.
    const int ncol_blk = N / GB_COLS;                          // 8
    const int nchunks  = (2 * N / GB_ROWS) * ncol_blk;         // 2048
    for (int c = blockIdx.x; c < nchunks; c += NBLK) {
        int bx   = c & (ncol_blk - 1);
        int by   = c / ncol_blk;
        int row0 = by * GB_ROWS;

        if (tid < GB_ROWS) hs[tid] = h_bn[row0 + tid];
        __syncthreads();

        int col = bx * GB_COLS + tid * 4;
        const float* Wp = W + (size_t)row0 * N + col;
        float ax = 0.0f, ay = 0.0f, az = 0.0f, aw = 0.0f;
#pragma unroll 8
        for (int r = 0; r < GB_ROWS; ++r) {
            float4 w = *(const float4*)Wp;
            float hv = hs[r];
            ax = fmaf(hv, w.x, ax);
            ay = fmaf(hv, w.y, ay);
            az = fmaf(hv, w.z, az);
            aw = fmaf(hv, w.w, aw);
            Wp += N;
        }
        *(float4*)(part + (size_t)by * N + col) = make_float4(ax, ay, az, aw);
        __syncthreads();
    }

    grid.sync();

    // ---- Phase C: reduce 2N/GB_ROWS partials per column + bias + exact gelu.
    // Blocks 0..N/64-1 each own 64 columns; wave reads are 256B coalesced.
    if (blockIdx.x < N / 64) {
        const int RY  = 2 * N / GB_ROWS;                       // 256
        int col = blockIdx.x * 64 + lane;
        float s = 0.0f;
        for (int ry = wv; ry < RY; ry += 4)
            s += part[(size_t)ry * N + col];
        sm[wv][lane] = s;
        __syncthreads();
        if (tid < 64) {
            float v = sm[0][lane] + sm[1][lane] + sm[2][lane] + sm[3][lane] + b[col];
            out[col] = 0.5f * v * (1.0f + erff(v * 0.70710678118654752f));
        }
    }
}

extern "C" void kernel_launch(void* const* d_in, const int* in_sizes, int n_in,
                              void* d_out, int out_size, void* d_ws, size_t ws_size,
                              hipStream_t stream)
{
    const float* x   = (const float*)d_in[0];   // [1, N]
    const int*   adj = (const int*)d_in[1];     // [N, K] (int32 per harness)
    // d_in[2] = edge_weights: unused by the reference
    const float* W   = (const float*)d_in[3];   // [2N, N]
    const float* b   = (const float*)d_in[4];   // [N]
    const float* g   = (const float*)d_in[5];   // bn_gamma [2N]
    const float* be  = (const float*)d_in[6];   // bn_beta  [2N]
    const float* mn  = (const float*)d_in[7];   // bn_mean  [2N]
    const float* vr  = (const float*)d_in[8];   // bn_var   [2N]
    float* out = (float*)d_out;

    int N = in_sizes[0];       // 8192
    int K = in_sizes[1] / N;   // 64
    int RY = (2 * N) / GB_ROWS; // 256 partial slices

    // Workspace: part [RY*N] floats (8 MiB) | h_bn [2N] floats. Every part
    // element is written in phase B before phase C reads it -> no zero-init.
    float* part = (float*)d_ws;
    float* h_bn = part + (size_t)RY * N;

    void* args[] = {
        (void*)&x, (void*)&adj, (void*)&g, (void*)&be, (void*)&mn, (void*)&vr,
        (void*)&W, (void*)&b, (void*)&part, (void*)&h_bn, (void*)&out,
        (void*)&N, (void*)&K
    };
    hipLaunchCooperativeKernel((void*)fused_gcn_kernel,
                               dim3(NBLK), dim3(NTHR), args, 0, stream);
}

// Round 5
// 709.818 us; speedup vs baseline: 1.2737x; 1.2737x over previous
//
#include <hip/hip_runtime.h>
#include <math.h>

#define BN_EPS 1e-3f

#define RPB 16        // rows of W per gemv block (contiguous 512KB slab)
#define NSTREAM 8     // float4 column-streams per thread: 256 thr * 4 * 8 = 8192 cols

// Kernel A: one 64-lane wave per node. adj row = coalesced 256B read; x is
// 32KB -> cache resident. Shuffle-reduce, lane 0 applies BN to both halves of
// h = concat([x, x + ngh_sum]).
__global__ void agg_bn_kernel(const float* __restrict__ x,
                              const int* __restrict__ adj,
                              const float* __restrict__ bn_gamma,
                              const float* __restrict__ bn_beta,
                              const float* __restrict__ bn_mean,
                              const float* __restrict__ bn_var,
                              float* __restrict__ h_bn,
                              int N, int K)
{
    int gid  = blockIdx.x * blockDim.x + threadIdx.x;
    int node = gid >> 6;
    int lane = gid & 63;
    if (node >= N) return;

    float s = 0.0f;
    for (int k = lane; k < K; k += 64)
        s += x[adj[(size_t)node * K + k]];
#pragma unroll
    for (int off = 32; off > 0; off >>= 1)
        s += __shfl_down(s, off, 64);

    if (lane == 0) {
        float xi  = x[node];
        float agg = xi + s;
        float sc0 = rsqrtf(bn_var[node] + BN_EPS) * bn_gamma[node];
        h_bn[node] = (xi - bn_mean[node]) * sc0 + bn_beta[node];
        int j = N + node;
        float sc1 = rsqrtf(bn_var[j] + BN_EPS) * bn_gamma[j];
        h_bn[j] = (agg - bn_mean[j]) * sc1 + bn_beta[j];
    }
}

// Kernel B: contiguous-slab split-K GEMV.
// Block b owns rows [16b, 16b+16) x ALL N cols: a contiguous 512KB slab of W
// (no 32KB-stride row walk -> no L1 set aliasing; DRAM-friendly sequential).
// Each thread: 8 independent float4 streams (cols tcol + s*1024),
// double-buffered loads (16 float4 loads in flight), 32 accumulators.
#define LOADROW(dst, r) {                                                  \
    const float4* p_ = Wrow + (size_t)(r) * Nq;                            \
    _Pragma("unroll")                                                      \
    for (int s_ = 0; s_ < NSTREAM; ++s_) dst[s_] = p_[s_ * 256]; }

#define FMAROW(src, r) {                                                   \
    float hv_ = hs[(r)];                                                   \
    _Pragma("unroll")                                                      \
    for (int s_ = 0; s_ < NSTREAM; ++s_) {                                 \
        acc[s_].x = fmaf(hv_, src[s_].x, acc[s_].x);                       \
        acc[s_].y = fmaf(hv_, src[s_].y, acc[s_].y);                       \
        acc[s_].z = fmaf(hv_, src[s_].z, acc[s_].z);                       \
        acc[s_].w = fmaf(hv_, src[s_].w, acc[s_].w); } }

__global__ __launch_bounds__(256, 4)
void gemv_slab_kernel(const float* __restrict__ h,
                      const float* __restrict__ W,
                      float* __restrict__ part,
                      int N)
{
    __shared__ float hs[RPB];
    int row0 = blockIdx.x * RPB;
    if (threadIdx.x < RPB) hs[threadIdx.x] = h[row0 + threadIdx.x];
    __syncthreads();

    const int tcol = threadIdx.x * 4;
    const int Nq = N >> 2;  // row length in float4 (2048)
    const float4* Wrow = (const float4*)(W + (size_t)row0 * N + tcol);

    float4 acc[NSTREAM];
#pragma unroll
    for (int s = 0; s < NSTREAM; ++s) acc[s] = make_float4(0.f, 0.f, 0.f, 0.f);

    float4 wA[NSTREAM], wB[NSTREAM];
    LOADROW(wA, 0);
#pragma unroll
    for (int r = 0; r < RPB; r += 2) {   // fully unrolled: all indices static
        LOADROW(wB, r + 1);
        FMAROW(wA, r);
        if (r + 2 < RPB) LOADROW(wA, r + 2);
        FMAROW(wB, r + 1);
    }

    // Stream s covers columns tcol + s*1024  ->  store at +s*(N>>3) floats.
    float* pp = part + (size_t)blockIdx.x * N + tcol;
#pragma unroll
    for (int s = 0; s < NSTREAM; ++s)
        *(float4*)(pp + s * (N >> 3)) = acc[s];
}

// Kernel C1: collapse 1024 partial rows -> 128. Block (g = b>>3, seg = b&7)
// reads 8 rows x 4KB contiguous segments, writes one 4KB segment.
__global__ __launch_bounds__(256)
void reduce8_kernel(const float* __restrict__ part,
                    float* __restrict__ part2,
                    int N)
{
    int g   = blockIdx.x >> 3;
    int seg = blockIdx.x & 7;
    int col = seg * (N >> 3) + threadIdx.x * 4;
    const float* p = part + (size_t)(g * 8) * N + col;
    float4 s = make_float4(0.f, 0.f, 0.f, 0.f);
#pragma unroll
    for (int i = 0; i < 8; ++i) {
        float4 v = *(const float4*)(p + (size_t)i * N);
        s.x += v.x; s.y += v.y; s.z += v.z; s.w += v.w;
    }
    *(float4*)(part2 + (size_t)g * N + col) = s;
}

// Kernel C2: reduce 128 partials per column + bias + exact-erf gelu.
__global__ __launch_bounds__(256)
void reduce_bias_gelu_kernel(const float* __restrict__ part2,
                             const float* __restrict__ b,
                             float* __restrict__ out,
                             int N, int G2)
{
    __shared__ float sm[4][64];
    int lane = threadIdx.x & 63;
    int wv   = threadIdx.x >> 6;
    int col  = blockIdx.x * 64 + lane;

    float s = 0.0f;
    for (int g = wv; g < G2; g += 4)
        s += part2[(size_t)g * N + col];
    sm[wv][lane] = s;
    __syncthreads();

    if (threadIdx.x < 64) {
        float v = sm[0][lane] + sm[1][lane] + sm[2][lane] + sm[3][lane] + b[col];
        out[col] = 0.5f * v * (1.0f + erff(v * 0.70710678118654752f));
    }
}

extern "C" void kernel_launch(void* const* d_in, const int* in_sizes, int n_in,
                              void* d_out, int out_size, void* d_ws, size_t ws_size,
                              hipStream_t stream)
{
    const float* x   = (const float*)d_in[0];   // [1, N]
    const int*   adj = (const int*)d_in[1];     // [N, K] (int32 per harness)
    // d_in[2] = edge_weights: unused by the reference
    const float* W   = (const float*)d_in[3];   // [2N, N]
    const float* b   = (const float*)d_in[4];   // [N]
    const float* g   = (const float*)d_in[5];   // bn_gamma [2N]
    const float* be  = (const float*)d_in[6];   // bn_beta  [2N]
    const float* mn  = (const float*)d_in[7];   // bn_mean  [2N]
    const float* vr  = (const float*)d_in[8];   // bn_var   [2N]
    float* out = (float*)d_out;

    int N  = in_sizes[0];        // 8192
    int K  = in_sizes[1] / N;    // 64
    int PB = (2 * N) / RPB;      // 1024 gemv blocks / partial rows
    int G2 = PB / 8;             // 128 stage-2 partial rows

    // Workspace: part [PB*N] (32MB) | part2 [G2*N] (4MB) | h_bn [2N].
    // Every element of part/part2 is written before it is read -> no memset.
    float* part  = (float*)d_ws;
    float* part2 = part + (size_t)PB * N;
    float* h_bn  = part2 + (size_t)G2 * N;

    {
        long long total_threads = (long long)N * 64;   // one wave per node
        int blocks = (int)((total_threads + 255) / 256);
        agg_bn_kernel<<<blocks, 256, 0, stream>>>(x, adj, g, be, mn, vr, h_bn, N, K);
    }
    gemv_slab_kernel<<<PB, 256, 0, stream>>>(h_bn, W, part, N);
    reduce8_kernel<<<PB, 256, 0, stream>>>(part, part2, N);
    reduce_bias_gelu_kernel<<<N / 64, 256, 0, stream>>>(part2, b, out, N, G2);
}